// Round 5
// baseline (291.799 us; speedup 1.0000x reference)
//
#include <hip/hip_runtime.h>

typedef __bf16 bf16x8 __attribute__((ext_vector_type(8)));
typedef float  f32x4  __attribute__((ext_vector_type(4)));

constexpr int BM = 128, BN = 128, BK = 32;
constexpr int MDIM = 65536, NDIM = 1152, KDIM = 768;
constexpr int NBN = NDIM / BN;          // 9
constexpr int NKT = KDIM / BK;          // 24
constexpr int GRID = (MDIM / BM) * NBN; // 4608 (divisible by 8 -> bijective XCD swizzle)
constexpr int LDSROWB = BK * 2;         // 64 B per tile row (32 bf16)

// ws holds "LDS images": per (panel, kt) an 8 KB block that is byte-for-byte the
// desired (XOR-swizzled) LDS tile. Staging is a linear contiguous copy
// (global_load_lds-compatible); ds_reads apply the same XOR.

__device__ __forceinline__ void gload16(const void* g, void* l) {
  __builtin_amdgcn_global_load_lds(
      (const __attribute__((address_space(1))) void*)g,
      (__attribute__((address_space(3))) void*)l, 16, 0, 0);
}

__device__ __forceinline__ unsigned pk2(float x, float y) {
  __bf16 a = (__bf16)x, b = (__bf16)y;
  return (unsigned)__builtin_bit_cast(unsigned short, a) |
         ((unsigned)__builtin_bit_cast(unsigned short, b) << 16);
}

// ---------------- fp32 -> bf16 swizzled-LDS-image repack ----------------
__global__ __launch_bounds__(256)
void repack_kernel(const float* __restrict__ in, __bf16* __restrict__ out) {
  const int c    = blockIdx.x * 256 + threadIdx.x;
  const int c_in = c & 511;        // chunk within 8KB image
  const int img  = c >> 9;
  const int kt   = img % NKT;
  const int pan  = img / NKT;      // 128-row panel index
  const int o = c_in * 16;         // swizzled (physical) offset
  const int u = (o >> 6) & 7;
  const int a = o ^ ((u ^ (u >> 2)) << 4);   // invert triangular XOR -> logical addr
  const int r = a >> 6;            // tile row 0..127
  const int p = (a >> 4) & 3;      // 16B part within row
  const float* src = in + (size_t)(pan * 128 + r) * KDIM + kt * 32 + p * 8;
  const float4 x = *reinterpret_cast<const float4*>(src);
  const float4 y = *reinterpret_cast<const float4*>(src + 4);
  uint4 r4;
  r4.x = pk2(x.x, x.y); r4.y = pk2(x.z, x.w);
  r4.z = pk2(y.x, y.y); r4.w = pk2(y.z, y.w);
  *reinterpret_cast<uint4*>(out + (size_t)c * 8) = r4;
}

// ---------------- main GEMM: swizzled-image staging, swapped-operand MFMA ----------
// acc[mf][nf] = mfma(B_frag[nf], A_frag[mf]) -> per-lane ROW-major C:
//   acc[mf][nf][reg] = C[bm*128 + wr*64 + mf*16 + (lane&15)]
//                       [bn*128 + wc*64 + nf*16 + (lane>>4)*4 + reg]
__global__ __launch_bounds__(256, 4)
void gemm_swz_kernel(const __bf16* __restrict__ Aimg,  // [512][24][8KB] swizzled images
                     const __bf16* __restrict__ Bimg,  // [9][24][8KB]
                     const int*   __restrict__ ss,
                     const float* __restrict__ bias,
                     const float* __restrict__ pos,
                     float* __restrict__ out) {
  __shared__ __bf16 As[2][BM * BK];
  __shared__ __bf16 Bs[2][BM * BK];

  const int tid  = threadIdx.x;
  const int lane = tid & 63;
  const int wid  = tid >> 6;
  const int wr   = wid >> 1;
  const int wc   = wid & 1;

  const int bidh = blockIdx.x;
  const int bid  = (bidh & 7) * (GRID / 8) + (bidh >> 3);
  const int bm   = bid / NBN;
  const int bn   = bid % NBN;

  auto stage = [&](int kt, int buf) {
    const __bf16* wsA = Aimg + ((size_t)(bm * NKT + kt) << 12);  // 4096 bf16 / image
    const __bf16* wsB = Bimg + ((size_t)(bn * NKT + kt) << 12);
    gload16(wsA + tid * 8,         (char*)(&As[buf][0]) + tid * 16);
    gload16(wsA + (256 + tid) * 8, (char*)(&As[buf][0]) + (256 + tid) * 16);
    gload16(wsB + tid * 8,         (char*)(&Bs[buf][0]) + tid * 16);
    gload16(wsB + (256 + tid) * 8, (char*)(&Bs[buf][0]) + (256 + tid) * 16);
  };

  f32x4 acc[4][4];
#pragma unroll
  for (int i = 0; i < 4; ++i)
#pragma unroll
    for (int j = 0; j < 4; ++j) acc[i][j] = (f32x4)0.0f;

  const int fr = lane & 15;
  const int kg = lane >> 4;
  const int abase = (((wr * 64 + fr) * LDSROWB) + kg * 16) ^ ((fr & 7) << 4);
  const int bbase = (((wc * 64 + fr) * LDSROWB) + kg * 16) ^ ((fr & 7) << 4);

  auto compute = [&](int buf) {
    const char* pa = reinterpret_cast<const char*>(&As[buf][0]);
    const char* pb = reinterpret_cast<const char*>(&Bs[buf][0]);
    bf16x8 af[4], bfv[4];
#pragma unroll
    for (int mf = 0; mf < 4; ++mf)
      af[mf] = *reinterpret_cast<const bf16x8*>(pa + abase + mf * 16 * LDSROWB);
#pragma unroll
    for (int nf = 0; nf < 4; ++nf)
      bfv[nf] = *reinterpret_cast<const bf16x8*>(pb + bbase + nf * 16 * LDSROWB);
#pragma unroll
    for (int mf = 0; mf < 4; ++mf)
#pragma unroll
      for (int nf = 0; nf < 4; ++nf)   // swapped operands -> row-major C fragment
        acc[mf][nf] = __builtin_amdgcn_mfma_f32_16x16x32_bf16(bfv[nf], af[mf], acc[mf][nf], 0, 0, 0);
  };

  stage(0, 0);
  for (int kt = 0; kt < NKT; ++kt) {
    const int cur = kt & 1;
    __syncthreads();                           // drains stage of buf[cur]
    if (kt + 1 < NKT) stage(kt + 1, cur ^ 1);  // async prefetch flies under MFMA
    compute(cur);
  }

  // ---------------- epilogue: float4 stores, 4 bilinear setups per lane ----------
  const int colq = bn * BN + wc * 64 + kg * 4;   // + nf*16 (+reg)
  f32x4 bias4[4];
#pragma unroll
  for (int nf = 0; nf < 4; ++nf)
    bias4[nf] = *reinterpret_cast<const f32x4*>(bias + colq + nf * 16);

  const int s  = bm >> 3;
  const int h  = ss[2 * s];
  const int w  = ss[2 * s + 1];
  const int hw = h * w;
  const float rh = 16.0f / (float)h;
  const float rw = 16.0f / (float)w;

#pragma unroll
  for (int mf = 0; mf < 4; ++mf) {
    const int row = bm * BM + wr * 64 + mf * 16 + fr;
    int p = row & 1023;
    if (p >= hw) p = 0;            // padded region replicates resized[0] == grid[0,0]
    const int y = p / w;
    const int x = p - y * w;
    const float fy = ((float)y + 0.5f) * rh - 0.5f;
    const float fx = ((float)x + 0.5f) * rw - 0.5f;
    const float yf = floorf(fy), xf = floorf(fx);
    const float ty = fy - yf,   tx = fx - xf;
    int iy0 = (int)yf, ix0 = (int)xf;
    int iy1 = iy0 + 1 > 15 ? 15 : iy0 + 1;
    int ix1 = ix0 + 1 > 15 ? 15 : ix0 + 1;
    iy0 = iy0 < 0 ? 0 : iy0;
    ix0 = ix0 < 0 ? 0 : ix0;
    const float* g00 = pos + (size_t)(iy0 * 16 + ix0) * NDIM;
    const float* g01 = pos + (size_t)(iy0 * 16 + ix1) * NDIM;
    const float* g10 = pos + (size_t)(iy1 * 16 + ix0) * NDIM;
    const float* g11 = pos + (size_t)(iy1 * 16 + ix1) * NDIM;
    float* orow = out + (size_t)row * NDIM;
#pragma unroll
    for (int nf = 0; nf < 4; ++nf) {
      const int col = colq + nf * 16;
      const f32x4 v00 = *reinterpret_cast<const f32x4*>(g00 + col);
      const f32x4 v01 = *reinterpret_cast<const f32x4*>(g01 + col);
      const f32x4 v10 = *reinterpret_cast<const f32x4*>(g10 + col);
      const f32x4 v11 = *reinterpret_cast<const f32x4*>(g11 + col);
      const f32x4 top = v00 + tx * (v01 - v00);
      const f32x4 bot = v10 + tx * (v11 - v10);
      const f32x4 pv  = top + ty * (bot - top);
      *reinterpret_cast<f32x4*>(orow + col) = acc[mf][nf] + bias4[nf] + pv;
    }
  }
}

// ---------------- fallback: fp32 inputs, reg-stage + on-the-fly convert (known-good) ----
__global__ __launch_bounds__(256, 2)
void gemm_fb_kernel(const float* __restrict__ A,
                    const int*   __restrict__ ss,
                    const float* __restrict__ Wm,
                    const float* __restrict__ bias,
                    const float* __restrict__ pos,
                    float* __restrict__ out) {
  __shared__ unsigned short As[2][BM * BK];
  __shared__ unsigned short Bs[2][BM * BK];

  const int tid  = threadIdx.x;
  const int lane = tid & 63;
  const int wid  = tid >> 6;
  const int wr   = wid >> 1;
  const int wc   = wid & 1;

  const int bidh = blockIdx.x;
  const int bid  = (bidh & 7) * (GRID / 8) + (bidh >> 3);
  const int bm   = bid / NBN;
  const int bn   = bid % NBN;

  const int srow0 = tid >> 3;
  const int skc   = tid & 7;
  const float* Ag = A  + (size_t)(bm * BM + srow0) * KDIM + skc * 4;
  const float* Bg = Wm + (size_t)(bn * BN + srow0) * KDIM + skc * 4;

  float4 ra[4], rb[4];

  auto stage_load = [&](int kt) {
    const int ko = kt * BK;
#pragma unroll
    for (int r = 0; r < 4; ++r) {
      ra[r] = *reinterpret_cast<const float4*>(Ag + (size_t)(r * 32) * KDIM + ko);
      rb[r] = *reinterpret_cast<const float4*>(Bg + (size_t)(r * 32) * KDIM + ko);
    }
  };

  auto stage_write = [&](int buf) {
#pragma unroll
    for (int r = 0; r < 4; ++r) {
      const int arow = r * 32 + srow0;
      int off = arow * LDSROWB + skc * 8;
      off ^= (arow & 7) << 4;
      uint2 pa, pb;
      pa.x = pk2(ra[r].x, ra[r].y); pa.y = pk2(ra[r].z, ra[r].w);
      pb.x = pk2(rb[r].x, rb[r].y); pb.y = pk2(rb[r].z, rb[r].w);
      *reinterpret_cast<uint2*>(reinterpret_cast<char*>(&As[buf][0]) + off) = pa;
      *reinterpret_cast<uint2*>(reinterpret_cast<char*>(&Bs[buf][0]) + off) = pb;
    }
  };

  f32x4 acc[4][4];
#pragma unroll
  for (int i = 0; i < 4; ++i)
#pragma unroll
    for (int j = 0; j < 4; ++j) acc[i][j] = (f32x4)0.0f;

  const int fr = lane & 15;
  const int kg = lane >> 4;
  int abase = (wr * 64 + fr) * LDSROWB + kg * 16; abase ^= (fr & 7) << 4;
  int bbase = (wc * 64 + fr) * LDSROWB + kg * 16; bbase ^= (fr & 7) << 4;

  auto compute = [&](int buf) {
    const char* pa = reinterpret_cast<const char*>(&As[buf][0]);
    const char* pb = reinterpret_cast<const char*>(&Bs[buf][0]);
    bf16x8 af[4], bfv[4];
#pragma unroll
    for (int mf = 0; mf < 4; ++mf)
      af[mf] = *reinterpret_cast<const bf16x8*>(pa + abase + mf * 16 * LDSROWB);
#pragma unroll
    for (int nf = 0; nf < 4; ++nf)
      bfv[nf] = *reinterpret_cast<const bf16x8*>(pb + bbase + nf * 16 * LDSROWB);
#pragma unroll
    for (int mf = 0; mf < 4; ++mf)
#pragma unroll
      for (int nf = 0; nf < 4; ++nf)
        acc[mf][nf] = __builtin_amdgcn_mfma_f32_16x16x32_bf16(af[mf], bfv[nf], acc[mf][nf], 0, 0, 0);
  };

  stage_load(0);
  stage_write(0);
  for (int kt = 0; kt < NKT; ++kt) {
    const int cur = kt & 1;
    if (kt + 1 < NKT) stage_load(kt + 1);
    __syncthreads();
    compute(cur);
    if (kt + 1 < NKT) stage_write(cur ^ 1);
  }

  // scalar epilogue (original layout: col=lane&15, row=kg*4+reg)
  const int colbase = bn * BN + wc * 64 + fr;
  float bvals[4];
#pragma unroll
  for (int nf = 0; nf < 4; ++nf) bvals[nf] = bias[colbase + nf * 16];

  const int s  = bm >> 3;
  const int h  = ss[2 * s];
  const int w  = ss[2 * s + 1];
  const int hw = h * w;
  const float rh = 16.0f / (float)h;
  const float rw = 16.0f / (float)w;
  const int row0 = bm * BM + wr * 64 + kg * 4;

#pragma unroll
  for (int mf = 0; mf < 4; ++mf) {
#pragma unroll
    for (int rg = 0; rg < 4; ++rg) {
      const int row = row0 + mf * 16 + rg;
      int p = row & 1023;
      if (p >= hw) p = 0;
      const int y = p / w;
      const int x = p - y * w;
      const float fy = ((float)y + 0.5f) * rh - 0.5f;
      const float fx = ((float)x + 0.5f) * rw - 0.5f;
      const float yf = floorf(fy), xf = floorf(fx);
      const float ty = fy - yf,   tx = fx - xf;
      int iy0 = (int)yf, ix0 = (int)xf;
      int iy1 = iy0 + 1 > 15 ? 15 : iy0 + 1;
      int ix1 = ix0 + 1 > 15 ? 15 : ix0 + 1;
      iy0 = iy0 < 0 ? 0 : iy0;
      ix0 = ix0 < 0 ? 0 : ix0;
      const float* g00 = pos + (size_t)(iy0 * 16 + ix0) * NDIM;
      const float* g01 = pos + (size_t)(iy0 * 16 + ix1) * NDIM;
      const float* g10 = pos + (size_t)(iy1 * 16 + ix0) * NDIM;
      const float* g11 = pos + (size_t)(iy1 * 16 + ix1) * NDIM;
      float* orow = out + (size_t)row * NDIM;
#pragma unroll
      for (int nf = 0; nf < 4; ++nf) {
        const int col = colbase + nf * 16;
        const float p00 = g00[col], p01 = g01[col];
        const float p10 = g10[col], p11 = g11[col];
        const float top = p00 + tx * (p01 - p00);
        const float bot = p10 + tx * (p11 - p10);
        const float pv  = top + ty * (bot - top);
        orow[col] = acc[mf][nf][rg] + bvals[nf] + pv;
      }
    }
  }
}

extern "C" void kernel_launch(void* const* d_in, const int* in_sizes, int n_in,
                              void* d_out, int out_size, void* d_ws, size_t ws_size,
                              hipStream_t stream) {
  const float* A    = (const float*)d_in[0];
  const int*   ss   = (const int*)d_in[1];
  const float* Wm   = (const float*)d_in[2];
  const float* bias = (const float*)d_in[3];
  const float* pos  = (const float*)d_in[4];
  float* out = (float*)d_out;

  const size_t needA = (size_t)MDIM * KDIM * 2;  // 100,663,296 B
  const size_t needW = (size_t)NDIM * KDIM * 2;  //   1,769,472 B

  if (ws_size >= needA + needW) {
    __bf16* Ab = (__bf16*)d_ws;
    __bf16* Bb = (__bf16*)((char*)d_ws + needA);
    const int chunksA = (MDIM / 16) * NKT * 64;  // 6,291,456 16B chunks
    const int chunksW = (NDIM / 16) * NKT * 64;  //   110,592
    repack_kernel<<<chunksA / 256, 256, 0, stream>>>(A, Ab);
    repack_kernel<<<chunksW / 256, 256, 0, stream>>>(Wm, Bb);
    gemm_swz_kernel<<<GRID, 256, 0, stream>>>(Ab, Bb, ss, bias, pos, out);
  } else {
    gemm_fb_kernel<<<GRID, 256, 0, stream>>>(A, ss, Wm, bias, pos, out);
  }
}